// Round 6
// baseline (553.089 us; speedup 1.0000x reference)
//
#include <hip/hip_runtime.h>
#include <cstdint>

#define B_    16
#define N_    128
#define P_    4096
#define M_    65536     // B_*P_
#define DIN   1024
#define DHID  512
#define DGEO  128
#define DEMB  200
#define NODEF 328       // DGEO + DEMB
#define NOBJ  151
#define OUTC  50
#define KGEO  656
#define KGEOP 704       // padded to multiple of 64 (BK=64)

typedef __attribute__((ext_vector_type(8))) short bf16x8;
typedef __attribute__((ext_vector_type(4))) float f32x4;

typedef __attribute__((address_space(3))) unsigned char lds_u8;
typedef __attribute__((address_space(1))) unsigned char glb_u8;

static __device__ __forceinline__ void async_copy16(const void* g, void* l) {
  __builtin_amdgcn_global_load_lds((const glb_u8*)g, (lds_u8*)l, 16, 0, 0);
}

static __device__ __forceinline__ unsigned short f2b(float f) {
  union { float f; unsigned u; } v; v.f = f;
  unsigned r = v.u + 0x7fffu + ((v.u >> 16) & 1u);
  return (unsigned short)(r >> 16);
}
static __device__ __forceinline__ float b2f(unsigned short b) {
  union { unsigned u; float f; } v; v.u = ((unsigned)b) << 16;
  return v.f;
}
static __device__ __forceinline__ unsigned pack2(float a, float b) {
  return (unsigned)f2b(a) | ((unsigned)f2b(b) << 16);
}
static __device__ __forceinline__ void unpack8(uint4 raw, float* x) {
  x[0] = b2f(raw.x & 0xffffu); x[1] = b2f(raw.x >> 16);
  x[2] = b2f(raw.y & 0xffffu); x[3] = b2f(raw.y >> 16);
  x[4] = b2f(raw.z & 0xffffu); x[5] = b2f(raw.z >> 16);
  x[6] = b2f(raw.w & 0xffffu); x[7] = b2f(raw.w >> 16);
}

// ---- fast zero fill (also provides the zero-source region for geo gather) ----
__global__ __launch_bounds__(256)
void zero_kernel(uint4* __restrict__ p) {
  p[blockIdx.x * 256 + threadIdx.x] = make_uint4(0, 0, 0, 0);
}

// ---- weight transpose + bf16 cast: wT[n][k] = w[k][n], zero-padded ----
__global__ void transpose_cvt(const float* __restrict__ w, unsigned short* __restrict__ wT,
                              int K, int Nw, int Kpad, int Npad) {
  int idx = blockIdx.x * blockDim.x + threadIdx.x;
  if (idx >= Npad * Kpad) return;
  int n = idx / Kpad, k = idx - n * Kpad;
  float v = (n < Nw && k < K) ? w[(size_t)k * Nw + n] : 0.f;
  wT[idx] = f2b(v);
}

// ---- per-node features (relu'd, bf16): nodeFb[node] = [relu(pos)(128), relu(sem)(200)] ----
__global__ __launch_bounds__(128)
void node_kernel(const float* __restrict__ box, const float* __restrict__ plog,
                 const float* __restrict__ semw,
                 const float* __restrict__ w1, const float* __restrict__ b1,
                 const float* __restrict__ w2, const float* __restrict__ b2,
                 unsigned short* __restrict__ nodeFb) {
  const int node = blockIdx.x;          // 0..2047
  const int t = threadIdx.x;            // 0..127 (2 waves)
  __shared__ float sBox[9];
  __shared__ float sH[128];
  __shared__ float sE[NOBJ];
  __shared__ float sRed[4];
  if (t < 9) sBox[t] = box[node * 9 + t];
  float l0 = (t < NOBJ) ? plog[node * NOBJ + t] : -1e30f;
  float l1 = (t + 128 < NOBJ) ? plog[node * NOBJ + t + 128] : -1e30f;
  __syncthreads();
  float h = b1[t];
#pragma unroll
  for (int i = 0; i < 9; i++) h = fmaf(sBox[i], w1[i * 128 + t], h);
  h = fmaxf(h, 0.f);
  sH[t] = h;
  float mx = fmaxf(l0, l1);
#pragma unroll
  for (int off = 32; off >= 1; off >>= 1) mx = fmaxf(mx, __shfl_xor(mx, off));
  if ((t & 63) == 0) sRed[t >> 6] = mx;
  __syncthreads();
  mx = fmaxf(sRed[0], sRed[1]);
  float e0 = (t < NOBJ) ? expf(l0 - mx) : 0.f;
  float e1 = (t + 128 < NOBJ) ? expf(l1 - mx) : 0.f;
  if (t < NOBJ) sE[t] = e0;
  if (t + 128 < NOBJ) sE[t + 128] = e1;
  float sm = e0 + e1;
#pragma unroll
  for (int off = 32; off >= 1; off >>= 1) sm += __shfl_xor(sm, off);
  if ((t & 63) == 0) sRed[2 + (t >> 6)] = sm;
  __syncthreads();
  const float inv = 1.f / (sRed[2] + sRed[3]);
  float pv = b2[t];
  for (int i = 0; i < 128; i++) pv = fmaf(sH[i], w2[i * 128 + t], pv);
  nodeFb[(size_t)node * NODEF + t] = f2b(fmaxf(pv, 0.f));
  float a0 = 0.f, a1 = 0.f;
  const int d1 = (t + 128 < DEMB) ? (t + 128) : 0;
  for (int i = 0; i < NOBJ; i++) {
    float e = sE[i];
    a0 = fmaf(e, semw[i * DEMB + t], a0);
    a1 = fmaf(e, semw[i * DEMB + d1], a1);
  }
  nodeFb[(size_t)node * NODEF + 128 + t] = f2b(fmaxf(a0 * inv, 0.f));
  if (t + 128 < DEMB) nodeFb[(size_t)node * NODEF + 128 + t + 128] = f2b(fmaxf(a1 * inv, 0.f));
}

// ---- relu + f32->bf16 cast (vectorized, grid-stride) ----
__global__ __launch_bounds__(256)
void relu_cast_kernel(const float* __restrict__ in, unsigned short* __restrict__ out, int n8) {
  for (int i = blockIdx.x * blockDim.x + threadIdx.x; i < n8; i += gridDim.x * blockDim.x) {
    float4 v0 = ((const float4*)in)[2 * i];
    float4 v1 = ((const float4*)in)[2 * i + 1];
    uint4 u;
    u.x = pack2(fmaxf(v0.x, 0.f), fmaxf(v0.y, 0.f));
    u.y = pack2(fmaxf(v0.z, 0.f), fmaxf(v0.w, 0.f));
    u.z = pack2(fmaxf(v1.x, 0.f), fmaxf(v1.y, 0.f));
    u.w = pack2(fmaxf(v1.z, 0.f), fmaxf(v1.w, 0.f));
    ((uint4*)out)[i] = u;
  }
}

// ---- fused LayerNorm + ReLU, in place, wave per row ----
template<int D>
__global__ __launch_bounds__(256)
void ln_relu_kernel(unsigned short* __restrict__ X,
                    const float* __restrict__ g, const float* __restrict__ bta) {
  constexpr int C = D / 64;                    // elems per lane (16 or 8)
  const int lane = threadIdx.x & 63, wv = threadIdx.x >> 6;
  const size_t row = (size_t)blockIdx.x * 4 + wv;
  unsigned short* xp = X + row * D + lane * C;
  float x[C];
#pragma unroll
  for (int c = 0; c < C; c += 8) {
    uint4 raw = *(const uint4*)(xp + c);
    unpack8(raw, x + c);
  }
  float s = 0.f, s2 = 0.f;
#pragma unroll
  for (int q = 0; q < C; q++) { s += x[q]; s2 = fmaf(x[q], x[q], s2); }
#pragma unroll
  for (int off = 32; off >= 1; off >>= 1) { s += __shfl_xor(s, off); s2 += __shfl_xor(s2, off); }
  const float mu = s / D;
  const float rs = rsqrtf(s2 / D - mu * mu + 1e-5f);
  const float* gp = g + lane * C;
  const float* bp = bta + lane * C;
#pragma unroll
  for (int c = 0; c < C; c += 8) {
    float4 g0 = *(const float4*)(gp + c), g1 = *(const float4*)(gp + c + 4);
    float4 t0 = *(const float4*)(bp + c), t1 = *(const float4*)(bp + c + 4);
    float y0 = fmaxf(fmaf((x[c + 0] - mu) * rs, g0.x, t0.x), 0.f);
    float y1 = fmaxf(fmaf((x[c + 1] - mu) * rs, g0.y, t0.y), 0.f);
    float y2 = fmaxf(fmaf((x[c + 2] - mu) * rs, g0.z, t0.z), 0.f);
    float y3 = fmaxf(fmaf((x[c + 3] - mu) * rs, g0.w, t0.w), 0.f);
    float y4 = fmaxf(fmaf((x[c + 4] - mu) * rs, g1.x, t1.x), 0.f);
    float y5 = fmaxf(fmaf((x[c + 5] - mu) * rs, g1.y, t1.y), 0.f);
    float y6 = fmaxf(fmaf((x[c + 6] - mu) * rs, g1.z, t1.z), 0.f);
    float y7 = fmaxf(fmaf((x[c + 7] - mu) * rs, g1.w, t1.w), 0.f);
    uint4 u;
    u.x = pack2(y0, y1); u.y = pack2(y2, y3);
    u.z = pack2(y4, y5); u.w = pack2(y6, y7);
    *(uint4*)(xp + c) = u;
  }
}

// ---- 128x128 m97-structure bf16 GEMM (proven 912 TF-class, ~32KB LDS, high occ) ----
// MODE 0: A = plain bf16 [M][lda]
// MODE 1: A = gathered pair rows from nodeFb (subj 0..327 | obj 328..655 | 0 pad)
//         via per-lane global_load_lds source select; lda ignored.
template<int MODE>
__global__ __launch_bounds__(256)
void gemm128(const unsigned short* __restrict__ A, int lda,
             const unsigned short* __restrict__ Bt,
             const float* __restrict__ bias,
             unsigned short* __restrict__ C, int ldc, int ccol0,
             int Ktot, int NBN,
             const int* __restrict__ pidx,
             const unsigned short* __restrict__ nodeFb,
             const unsigned short* __restrict__ zsrc) {
  __shared__ unsigned short ldsA[128 * 64];
  __shared__ unsigned short ldsB[128 * 64];
  const int tid = threadIdx.x;
  const int lane = tid & 63, wid = tid >> 6;
  // bijective XCD swizzle (gridDim.x % 8 == 0)
  const int cpx = gridDim.x >> 3;
  const int swz = (blockIdx.x & 7) * cpx + (blockIdx.x >> 3);
  const int bm = swz / NBN, bn = swz - bm * NBN;

  // staging: wave covers rows [wid*32, wid*32+32) via 4 instrs of 8 rows
  const int srow = wid * 32 + (lane >> 3);
  const int skof = (lane & 7) * 8;
  const unsigned short* ag = A + (size_t)(bm * 128 + srow) * lda + skof;
  const unsigned short* bg = Bt + (size_t)(bn * 128 + srow) * Ktot + skof;

  const unsigned short* pS[4];
  const unsigned short* pO[4];
  if (MODE == 1) {
#pragma unroll
    for (int i = 0; i < 4; i++) {
      const int row = bm * 128 + srow + i * 8;
      int2 so = *(const int2*)(pidx + 2 * row);
      const int b = row >> 12;
      pS[i] = nodeFb + (size_t)((b << 7) + so.x) * NODEF;
      pO[i] = nodeFb + (size_t)((b << 7) + so.y) * NODEF;
    }
  }

  f32x4 acc[4][4];
#pragma unroll
  for (int m = 0; m < 4; m++)
#pragma unroll
    for (int n = 0; n < 4; n++) acc[m][n] = (f32x4){0.f, 0.f, 0.f, 0.f};

  const int wm = wid >> 1, wn = wid & 1;
  const int frow = lane & 15;
  const int kgrp = (lane >> 4) << 3;

  for (int kt = 0; kt < Ktot; kt += 64) {
    if (MODE == 0) {
#pragma unroll
      for (int i = 0; i < 4; i++)
        async_copy16(ag + (size_t)i * 8 * lda + kt, &ldsA[wid * 2048 + i * 512]);
    } else {
      const int k = kt + skof;
      const unsigned short* srcS = (k < NODEF) ? (pS[0] + k)
                                 : (k < KGEO) ? (pO[0] + (k - NODEF)) : zsrc;
      async_copy16(srcS, &ldsA[wid * 2048 + 0 * 512]);
#pragma unroll
      for (int i = 1; i < 4; i++) {
        const unsigned short* src = (k < NODEF) ? (pS[i] + k)
                                  : (k < KGEO) ? (pO[i] + (k - NODEF)) : zsrc;
        async_copy16(src, &ldsA[wid * 2048 + i * 512]);
      }
    }
#pragma unroll
    for (int i = 0; i < 4; i++)
      async_copy16(bg + (size_t)i * 8 * Ktot + kt, &ldsB[wid * 2048 + i * 512]);
    __syncthreads();
#pragma unroll
    for (int kk = 0; kk < 64; kk += 32) {
      bf16x8 af[4], bfr[4];
#pragma unroll
      for (int m = 0; m < 4; m++)
        af[m] = *(const bf16x8*)&ldsA[(wm * 64 + m * 16 + frow) * 64 + kk + kgrp];
#pragma unroll
      for (int n = 0; n < 4; n++)
        bfr[n] = *(const bf16x8*)&ldsB[(wn * 64 + n * 16 + frow) * 64 + kk + kgrp];
#pragma unroll
      for (int m = 0; m < 4; m++)
#pragma unroll
        for (int n = 0; n < 4; n++)
          acc[m][n] = __builtin_amdgcn_mfma_f32_16x16x32_bf16(af[m], bfr[n], acc[m][n], 0, 0, 0);
    }
    __syncthreads();
  }
  // epilogue: C/D layout col=lane&15, row=(lane>>4)*4+i
  const int rb = bm * 128 + wm * 64 + ((lane >> 4) << 2);
  const int cbl = wn * 64 + frow;
#pragma unroll
  for (int n = 0; n < 4; n++) {
    const int col = bn * 128 + cbl + n * 16;
    const float bv = bias[col];
#pragma unroll
    for (int m = 0; m < 4; m++)
#pragma unroll
      for (int i = 0; i < 4; i++) {
        const int row = rb + m * 16 + i;
        C[(size_t)row * ldc + ccol0 + col] = f2b(acc[m][n][i] + bv);
      }
  }
}

// ---- 128x128 m97-structure GEMM for cls layer (N=50) + fused score scatter ----
__global__ __launch_bounds__(256)
void gemm_cls(const unsigned short* __restrict__ A, int lda,
              const unsigned short* __restrict__ Bt,
              const float* __restrict__ bias,
              float* __restrict__ C,
              int Ktot,
              const int* __restrict__ pidx,
              unsigned long long* __restrict__ scat) {
  __shared__ unsigned short ldsA[128 * 64];
  __shared__ unsigned short ldsB[128 * 64];
  const int tid = threadIdx.x;
  const int lane = tid & 63, wid = tid >> 6;
  const int cpx = gridDim.x >> 3;
  const int bm = (blockIdx.x & 7) * cpx + (blockIdx.x >> 3);

  const int srow = wid * 32 + (lane >> 3);
  const int skof = (lane & 7) * 8;
  const unsigned short* ag = A + (size_t)(bm * 128 + srow) * lda + skof;
  const unsigned short* bg = Bt + (size_t)srow * Ktot + skof;

  f32x4 acc[4][4];
#pragma unroll
  for (int m = 0; m < 4; m++)
#pragma unroll
    for (int n = 0; n < 4; n++) acc[m][n] = (f32x4){0.f, 0.f, 0.f, 0.f};

  const int wm = wid >> 1, wn = wid & 1;
  const int frow = lane & 15;
  const int kgrp = (lane >> 4) << 3;

  for (int kt = 0; kt < Ktot; kt += 64) {
#pragma unroll
    for (int i = 0; i < 4; i++) {
      async_copy16(ag + (size_t)i * 8 * lda + kt, &ldsA[wid * 2048 + i * 512]);
      async_copy16(bg + (size_t)i * 8 * Ktot + kt, &ldsB[wid * 2048 + i * 512]);
    }
    __syncthreads();
#pragma unroll
    for (int kk = 0; kk < 64; kk += 32) {
      bf16x8 af[4], bfr[4];
#pragma unroll
      for (int m = 0; m < 4; m++)
        af[m] = *(const bf16x8*)&ldsA[(wm * 64 + m * 16 + frow) * 64 + kk + kgrp];
#pragma unroll
      for (int n = 0; n < 4; n++)
        bfr[n] = *(const bf16x8*)&ldsB[(wn * 64 + n * 16 + frow) * 64 + kk + kgrp];
#pragma unroll
      for (int m = 0; m < 4; m++)
#pragma unroll
        for (int n = 0; n < 4; n++)
          acc[m][n] = __builtin_amdgcn_mfma_f32_16x16x32_bf16(af[m], bfr[n], acc[m][n], 0, 0, 0);
    }
    __syncthreads();
  }
  const int rb = bm * 128 + wm * 64 + ((lane >> 4) << 2);
#pragma unroll
  for (int n = 0; n < 4; n++) {
    const int col = wn * 64 + frow + n * 16;
    const float bv = (col < OUTC) ? bias[col] : 0.f;
#pragma unroll
    for (int m = 0; m < 4; m++)
#pragma unroll
      for (int i = 0; i < 4; i++) {
        const int row = rb + m * 16 + i;
        if (col < OUTC) C[(size_t)row * OUTC + col] = acc[m][n][i] + bv;
      }
  }
  // fused score: wn==0 waves hold cols 0..63 of their 64 rows
  if (wn == 0) {
#pragma unroll
    for (int m = 0; m < 4; m++)
#pragma unroll
      for (int i = 0; i < 4; i++) {
        float mx = -1e30f;
#pragma unroll
        for (int n = 0; n < 4; n++) {
          const int col = n * 16 + frow;
          float v = acc[m][n][i] + ((col < OUTC) ? bias[col] : 0.f);
          if (col < OUTC) mx = fmaxf(mx, v);
        }
        mx = fmaxf(mx, __shfl_xor(mx, 1));
        mx = fmaxf(mx, __shfl_xor(mx, 2));
        mx = fmaxf(mx, __shfl_xor(mx, 4));
        mx = fmaxf(mx, __shfl_xor(mx, 8));
        if (frow == 0) {
          const int row = rb + m * 16 + i;
          float sc = 1.f / (1.f + expf(-mx));
          int b = row >> 12, p = row & 4095;
          int s = pidx[2 * row], o = pidx[2 * row + 1];
          unsigned long long key = (((unsigned long long)(p + 1)) << 32) |
                                   (unsigned long long)__float_as_uint(sc);
          atomicMax(&scat[((size_t)(b * N_ + s) << 7) + o], key);
        }
      }
  }
}

__global__ void relmat_kernel(const unsigned long long* __restrict__ scat, float* __restrict__ out) {
  int i = blockIdx.x * blockDim.x + threadIdx.x;
  if (i >= B_ * N_ * N_) return;
  unsigned long long v = scat[i];
  out[i] = v ? __uint_as_float((unsigned)(v & 0xffffffffu)) : 0.f;
}

extern "C" void kernel_launch(void* const* d_in, const int* in_sizes, int n_in,
                              void* d_out, int out_size, void* d_ws, size_t ws_size,
                              hipStream_t stream) {
  const float* visual_feat = (const float*)d_in[0];
  const float* box_info    = (const float*)d_in[1];
  const float* pred_logits = (const float*)d_in[2];
  const int*   pair_idx    = (const int*)d_in[3];
  const float* obj_sem_w   = (const float*)d_in[4];
  const float* pos_w1 = (const float*)d_in[5];
  const float* pos_b1 = (const float*)d_in[6];
  const float* pos_w2 = (const float*)d_in[7];
  const float* pos_b2 = (const float*)d_in[8];
  const float* vis_w  = (const float*)d_in[9];
  const float* vis_b  = (const float*)d_in[10];
  const float* geo_w  = (const float*)d_in[11];
  const float* geo_b  = (const float*)d_in[12];
  const float* fus_g  = (const float*)d_in[13];
  const float* fus_bt = (const float*)d_in[14];
  const float* fus_w  = (const float*)d_in[15];
  const float* fus_b  = (const float*)d_in[16];
  const float* cls_g  = (const float*)d_in[17];
  const float* cls_bt = (const float*)d_in[18];
  const float* cls_w  = (const float*)d_in[19];
  const float* cls_b  = (const float*)d_in[20];

  char* ws = (char*)d_ws;
  size_t off = 0;
  auto alloc = [&](size_t bytes) { char* p = ws + off; off += (bytes + 255) & ~(size_t)255; return p; };
  unsigned short* fused = (unsigned short*)alloc((size_t)M_ * 1024 * 2);      // 134 MB
  unsigned short* R1    = (unsigned short*)alloc((size_t)M_ * 1024 * 2);      // 134 MB: visA -> fused2
  unsigned short* nodeFb = (unsigned short*)alloc((size_t)B_ * N_ * NODEF * 2);
  unsigned short* wT_vis = (unsigned short*)alloc((size_t)512 * 1024 * 2);
  unsigned short* wT_geo = (unsigned short*)alloc((size_t)512 * KGEOP * 2);
  unsigned short* wT_fus = (unsigned short*)alloc((size_t)512 * 1024 * 2);
  unsigned short* wT_cls = (unsigned short*)alloc((size_t)128 * 512 * 2);
  unsigned long long* scat = (unsigned long long*)alloc((size_t)B_ * N_ * N_ * 8);

  unsigned short* visA   = R1;      // [M][1024]
  unsigned short* fused2 = R1;      // [M][512]  (after vis GEMM consumed visA)

  float* out_logits = (float*)d_out;
  float* out_rel = out_logits + (size_t)M_ * OUTC;

  // scat zeroed first: doubles as the zero-source for geo gather staging
  zero_kernel<<<dim3(B_ * N_ * N_ * 8 / 4096), 256, 0, stream>>>((uint4*)scat);
  transpose_cvt<<<dim3((512 * 1024 + 255) / 256), 256, 0, stream>>>(vis_w, wT_vis, 1024, 512, 1024, 512);
  transpose_cvt<<<dim3((512 * KGEOP + 255) / 256), 256, 0, stream>>>(geo_w, wT_geo, KGEO, 512, KGEOP, 512);
  transpose_cvt<<<dim3((512 * 1024 + 255) / 256), 256, 0, stream>>>(fus_w, wT_fus, 1024, 512, 1024, 512);
  transpose_cvt<<<dim3((128 * 512 + 255) / 256), 256, 0, stream>>>(cls_w, wT_cls, 512, OUTC, 512, 128);
  node_kernel<<<dim3(B_ * N_), 128, 0, stream>>>(box_info, pred_logits, obj_sem_w,
                                                 pos_w1, pos_b1, pos_w2, pos_b2, nodeFb);
  // geo GEMM with fused pair-gather (A from nodeFb via per-lane gload_lds src)
  gemm128<1><<<dim3(512 * 4), 256, 0, stream>>>(nullptr, 0, wT_geo, geo_b,
                                                fused, 1024, 512, KGEOP, 4,
                                                pair_idx, nodeFb, (const unsigned short*)scat);
  relu_cast_kernel<<<dim3(2048), 256, 0, stream>>>(visual_feat, visA, M_ * 1024 / 8);
  gemm128<0><<<dim3(512 * 4), 256, 0, stream>>>(visA, 1024, wT_vis, vis_b,
                                                fused, 1024, 0, 1024, 4,
                                                nullptr, nullptr, nullptr);
  ln_relu_kernel<1024><<<dim3(M_ / 4), 256, 0, stream>>>(fused, fus_g, fus_bt);
  gemm128<0><<<dim3(512 * 4), 256, 0, stream>>>(fused, 1024, wT_fus, fus_b,
                                                fused2, 512, 0, 1024, 4,
                                                nullptr, nullptr, nullptr);
  ln_relu_kernel<512><<<dim3(M_ / 4), 256, 0, stream>>>(fused2, cls_g, cls_bt);
  gemm_cls<<<dim3(512), 256, 0, stream>>>(fused2, 512, wT_cls, cls_b,
                                          out_logits, 512, pair_idx, scat);
  relmat_kernel<<<dim3((B_ * N_ * N_) / 256), 256, 0, stream>>>(scat, out_rel);
}

// Round 7
// 442.859 us; speedup vs baseline: 1.2489x; 1.2489x over previous
//
#include <hip/hip_runtime.h>
#include <cstdint>

#define B_    16
#define N_    128
#define P_    4096
#define M_    65536     // B_*P_
#define DIN   1024
#define DHID  512
#define DGEO  128
#define DEMB  200
#define NODEF 328       // DGEO + DEMB
#define NOBJ  151
#define OUTC  50
#define KGEO  656
#define KGEOP 672       // padded to multiple of 32 (ring BK=32)

typedef __attribute__((ext_vector_type(8))) short bf16x8;
typedef __attribute__((ext_vector_type(4))) float f32x4;

typedef __attribute__((address_space(3))) unsigned char lds_u8;
typedef __attribute__((address_space(1))) unsigned char glb_u8;

static __device__ __forceinline__ void async_copy16(const void* g, void* l) {
  __builtin_amdgcn_global_load_lds((const glb_u8*)g, (lds_u8*)l, 16, 0, 0);
}

static __device__ __forceinline__ unsigned short f2b(float f) {
  union { float f; unsigned u; } v; v.f = f;
  unsigned r = v.u + 0x7fffu + ((v.u >> 16) & 1u);
  return (unsigned short)(r >> 16);
}
static __device__ __forceinline__ float b2f(unsigned short b) {
  union { unsigned u; float f; } v; v.u = ((unsigned)b) << 16;
  return v.f;
}
static __device__ __forceinline__ unsigned pack2(float a, float b) {
  return (unsigned)f2b(a) | ((unsigned)f2b(b) << 16);
}
static __device__ __forceinline__ void unpack8(uint4 raw, float* x) {
  x[0] = b2f(raw.x & 0xffffu); x[1] = b2f(raw.x >> 16);
  x[2] = b2f(raw.y & 0xffffu); x[3] = b2f(raw.y >> 16);
  x[4] = b2f(raw.z & 0xffffu); x[5] = b2f(raw.z >> 16);
  x[6] = b2f(raw.w & 0xffffu); x[7] = b2f(raw.w >> 16);
}

// ---- merged prologue: zero scat + all 4 weight transposes in one launch ----
#define ZN   131072                    // scat zero, uint4 count (2 MB)
#define TV   (512 * 1024)              // wT_vis elems
#define TG   (512 * KGEOP)             // wT_geo elems
#define TF   (512 * 1024)              // wT_fus elems
#define TC   (128 * 512)               // wT_cls elems
#define PREP_TOT (ZN + TV + TG + TF + TC)
__global__ __launch_bounds__(256)
void prep_kernel(uint4* __restrict__ scat,
                 const float* __restrict__ vis_w, unsigned short* __restrict__ wT_vis,
                 const float* __restrict__ geo_w, unsigned short* __restrict__ wT_geo,
                 const float* __restrict__ fus_w, unsigned short* __restrict__ wT_fus,
                 const float* __restrict__ cls_w, unsigned short* __restrict__ wT_cls) {
  int idx = blockIdx.x * 256 + threadIdx.x;
  if (idx < ZN) { scat[idx] = make_uint4(0, 0, 0, 0); return; }
  idx -= ZN;
  if (idx < TV) {
    int n = idx >> 10, k = idx & 1023;
    wT_vis[idx] = f2b(vis_w[(size_t)k * 512 + n]);
    return;
  }
  idx -= TV;
  if (idx < TG) {
    int n = idx / KGEOP, k = idx - n * KGEOP;
    wT_geo[idx] = (k < KGEO) ? f2b(geo_w[(size_t)k * 512 + n]) : 0;
    return;
  }
  idx -= TG;
  if (idx < TF) {
    int n = idx >> 10, k = idx & 1023;
    wT_fus[idx] = f2b(fus_w[(size_t)k * 512 + n]);
    return;
  }
  idx -= TF;
  if (idx < TC) {
    int n = idx >> 9, k = idx & 511;
    wT_cls[idx] = (n < OUTC) ? f2b(cls_w[(size_t)k * OUTC + n]) : 0;
  }
}

// ---- per-node features (relu'd, bf16): nodeFb[node] = [relu(pos)(128), relu(sem)(200)] ----
__global__ __launch_bounds__(128)
void node_kernel(const float* __restrict__ box, const float* __restrict__ plog,
                 const float* __restrict__ semw,
                 const float* __restrict__ w1, const float* __restrict__ b1,
                 const float* __restrict__ w2, const float* __restrict__ b2,
                 unsigned short* __restrict__ nodeFb) {
  const int node = blockIdx.x;
  const int t = threadIdx.x;
  __shared__ float sBox[9];
  __shared__ float sH[128];
  __shared__ float sE[NOBJ];
  __shared__ float sRed[4];
  if (t < 9) sBox[t] = box[node * 9 + t];
  float l0 = (t < NOBJ) ? plog[node * NOBJ + t] : -1e30f;
  float l1 = (t + 128 < NOBJ) ? plog[node * NOBJ + t + 128] : -1e30f;
  __syncthreads();
  float h = b1[t];
#pragma unroll
  for (int i = 0; i < 9; i++) h = fmaf(sBox[i], w1[i * 128 + t], h);
  h = fmaxf(h, 0.f);
  sH[t] = h;
  float mx = fmaxf(l0, l1);
#pragma unroll
  for (int off = 32; off >= 1; off >>= 1) mx = fmaxf(mx, __shfl_xor(mx, off));
  if ((t & 63) == 0) sRed[t >> 6] = mx;
  __syncthreads();
  mx = fmaxf(sRed[0], sRed[1]);
  float e0 = (t < NOBJ) ? expf(l0 - mx) : 0.f;
  float e1 = (t + 128 < NOBJ) ? expf(l1 - mx) : 0.f;
  if (t < NOBJ) sE[t] = e0;
  if (t + 128 < NOBJ) sE[t + 128] = e1;
  float sm = e0 + e1;
#pragma unroll
  for (int off = 32; off >= 1; off >>= 1) sm += __shfl_xor(sm, off);
  if ((t & 63) == 0) sRed[2 + (t >> 6)] = sm;
  __syncthreads();
  const float inv = 1.f / (sRed[2] + sRed[3]);
  float pv = b2[t];
  for (int i = 0; i < 128; i++) pv = fmaf(sH[i], w2[i * 128 + t], pv);
  nodeFb[(size_t)node * NODEF + t] = f2b(fmaxf(pv, 0.f));
  float a0 = 0.f, a1 = 0.f;
  const int d1 = (t + 128 < DEMB) ? (t + 128) : 0;
  for (int i = 0; i < NOBJ; i++) {
    float e = sE[i];
    a0 = fmaf(e, semw[i * DEMB + t], a0);
    a1 = fmaf(e, semw[i * DEMB + d1], a1);
  }
  nodeFb[(size_t)node * NODEF + 128 + t] = f2b(fmaxf(a0 * inv, 0.f));
  if (t + 128 < DEMB) nodeFb[(size_t)node * NODEF + 128 + t + 128] = f2b(fmaxf(a1 * inv, 0.f));
}

// ---- fused LayerNorm + ReLU, in place, wave per row ----
template<int D>
__global__ __launch_bounds__(256)
void ln_relu_kernel(unsigned short* __restrict__ X,
                    const float* __restrict__ g, const float* __restrict__ bta) {
  constexpr int C = D / 64;
  const int lane = threadIdx.x & 63, wv = threadIdx.x >> 6;
  const size_t row = (size_t)blockIdx.x * 4 + wv;
  unsigned short* xp = X + row * D + lane * C;
  float x[C];
#pragma unroll
  for (int c = 0; c < C; c += 8) {
    uint4 raw = *(const uint4*)(xp + c);
    unpack8(raw, x + c);
  }
  float s = 0.f, s2 = 0.f;
#pragma unroll
  for (int q = 0; q < C; q++) { s += x[q]; s2 = fmaf(x[q], x[q], s2); }
#pragma unroll
  for (int off = 32; off >= 1; off >>= 1) { s += __shfl_xor(s, off); s2 += __shfl_xor(s2, off); }
  const float mu = s / D;
  const float rs = rsqrtf(s2 / D - mu * mu + 1e-5f);
  const float* gp = g + lane * C;
  const float* bp = bta + lane * C;
#pragma unroll
  for (int c = 0; c < C; c += 8) {
    float4 g0 = *(const float4*)(gp + c), g1 = *(const float4*)(gp + c + 4);
    float4 t0 = *(const float4*)(bp + c), t1 = *(const float4*)(bp + c + 4);
    float y0 = fmaxf(fmaf((x[c + 0] - mu) * rs, g0.x, t0.x), 0.f);
    float y1 = fmaxf(fmaf((x[c + 1] - mu) * rs, g0.y, t0.y), 0.f);
    float y2 = fmaxf(fmaf((x[c + 2] - mu) * rs, g0.z, t0.z), 0.f);
    float y3 = fmaxf(fmaf((x[c + 3] - mu) * rs, g0.w, t0.w), 0.f);
    float y4 = fmaxf(fmaf((x[c + 4] - mu) * rs, g1.x, t1.x), 0.f);
    float y5 = fmaxf(fmaf((x[c + 5] - mu) * rs, g1.y, t1.y), 0.f);
    float y6 = fmaxf(fmaf((x[c + 6] - mu) * rs, g1.z, t1.z), 0.f);
    float y7 = fmaxf(fmaf((x[c + 7] - mu) * rs, g1.w, t1.w), 0.f);
    uint4 u;
    u.x = pack2(y0, y1); u.y = pack2(y2, y3);
    u.z = pack2(y4, y5); u.w = pack2(y6, y7);
    *(uint4*)(xp + c) = u;
  }
}

// ---- pair-XCD swizzle: bn-siblings (bid=2k,2k+1) land on the SAME XCD ----
// bijective for nwg % 16 == 0 (nwg=512 here)
static __device__ __forceinline__ int pair_swz(int bid, int nwg) {
  const int cpx2 = nwg >> 4;                 // pairs per XCD
  const int pr = bid >> 1, q = bid & 1;
  return (((pr & 7) * cpx2) + (pr >> 3)) * 2 + q;
}

// ---- 256x256 ring-4 pipelined bf16 GEMM, BK=32, distance-3 prefetch (R5, proven) ----
// MODE 0: A = plain bf16.  MODE 1: A = gathered pair rows from nodeFb.
template<int MODE>
__global__ __launch_bounds__(512)
void gemm256r(const unsigned short* __restrict__ A, int ldaE,
              const unsigned short* __restrict__ Bt, int ldbE,
              const float* __restrict__ bias,
              unsigned short* __restrict__ C, int ldcE, int ccol0,
              int NS, int NBN,
              const int* __restrict__ pidx,
              const unsigned short* __restrict__ nodeFb,
              const unsigned short* __restrict__ zsrc) {
  __shared__ __align__(16) unsigned char smem[131072];
  const int tid = threadIdx.x;
  const int lane = tid & 63, w = tid >> 6;
  const int swz = pair_swz(blockIdx.x, gridDim.x);
  const int bm = swz / NBN, bn = swz - bm * NBN;

  const int sslot = (tid & 3) ^ ((tid >> 3) & 3);
  const int srow = tid >> 2;
  const size_t ldaBy = (size_t)ldaE * 2, ldbBy = (size_t)ldbE * 2;
  const unsigned char* aG = (const unsigned char*)A + (size_t)(bm * 256 + srow) * ldaBy + sslot * 16;
  const unsigned char* bG = (const unsigned char*)Bt + (size_t)(bn * 256 + srow) * ldbBy + sslot * 16;

  const unsigned short* nbS[2];
  const unsigned short* nbO[2];
  if (MODE == 1) {
#pragma unroll
    for (int r = 0; r < 2; r++) {
      int pr = bm * 256 + r * 128 + srow;
      int2 so = *(const int2*)(pidx + 2 * pr);
      int b = pr >> 12;
      nbS[r] = nodeFb + (size_t)((b << 7) + so.x) * NODEF;
      nbO[r] = nodeFb + (size_t)((b << 7) + so.y) * NODEF;
    }
  }

  auto stage = [&](int s) {
    const int slot = s & 3;
    unsigned char* la = smem + slot * 16384 + w * 1024;
    unsigned char* lb = smem + 65536 + slot * 16384 + w * 1024;
    if (MODE == 0) {
      const unsigned char* sa = aG + (size_t)s * 64;
      async_copy16(sa, la);
      async_copy16(sa + 128 * ldaBy, la + 8192);
    } else {
      const int e = s * 32 + sslot * 8;
#pragma unroll
      for (int r = 0; r < 2; r++) {
        uintptr_t ps = (uintptr_t)(nbS[r] + e);
        uintptr_t po = (uintptr_t)(nbO[r] + (e - NODEF));
        uintptr_t pz = (uintptr_t)zsrc;
        uintptr_t sel = (e < NODEF) ? ps : ((e < KGEO) ? po : pz);
        async_copy16((const void*)sel, la + r * 8192);
      }
    }
    const unsigned char* sb = bG + (size_t)s * 64;
    async_copy16(sb, lb);
    async_copy16(sb + 128 * ldbBy, lb + 8192);
  };

  const int wm = w >> 2, wn = w & 3;
  const int frow = lane & 15;
  const int colb = (((lane >> 4) ^ ((frow >> 1) & 3)) << 4);
  const int aRowB = (wm * 128 + frow) * 64;
  const int bRowB = (wn * 64 + frow) * 64;

  f32x4 acc[8][4];
#pragma unroll
  for (int m = 0; m < 8; m++)
#pragma unroll
    for (int n = 0; n < 4; n++) acc[m][n] = (f32x4){0.f, 0.f, 0.f, 0.f};

  stage(0); stage(1); stage(2);
  for (int s = 0; s < NS; ++s) {
    if (s == NS - 1)      asm volatile("s_waitcnt vmcnt(0)" ::: "memory");
    else if (s == NS - 2) asm volatile("s_waitcnt vmcnt(4)" ::: "memory");
    else                  asm volatile("s_waitcnt vmcnt(8)" ::: "memory");
    __builtin_amdgcn_s_barrier();
    __builtin_amdgcn_sched_barrier(0);
    if (s + 3 < NS) stage(s + 3);
    const unsigned char* ab = smem + (s & 3) * 16384;
    const unsigned char* bb = smem + 65536 + (s & 3) * 16384;
    bf16x8 af[8], bfv[4];
#pragma unroll
    for (int m = 0; m < 8; m++) af[m] = *(const bf16x8*)(ab + aRowB + m * 1024 + colb);
#pragma unroll
    for (int n = 0; n < 4; n++) bfv[n] = *(const bf16x8*)(bb + bRowB + n * 1024 + colb);
    __builtin_amdgcn_s_setprio(1);
#pragma unroll
    for (int m = 0; m < 8; m++)
#pragma unroll
      for (int n = 0; n < 4; n++)
        acc[m][n] = __builtin_amdgcn_mfma_f32_16x16x32_bf16(af[m], bfv[n], acc[m][n], 0, 0, 0);
    __builtin_amdgcn_s_setprio(0);
    __builtin_amdgcn_sched_barrier(0);
  }
  const int rb = bm * 256 + wm * 128 + ((lane >> 4) << 2);
  const int cb = bn * 256 + wn * 64 + frow;
#pragma unroll
  for (int n = 0; n < 4; n++) {
    const int col = cb + n * 16;
    const float bv = bias[col];
#pragma unroll
    for (int m = 0; m < 8; m++)
#pragma unroll
      for (int i = 0; i < 4; i++) {
        const int row = rb + m * 16 + i;
        C[(size_t)row * ldcE + ccol0 + col] = f2b(acc[m][n][i] + bv);
      }
  }
}

// ---- 256x256 ring-4 GEMM with A staged from f32 + relu + cvt (fused relu_cast) ----
// A f32 [M][1024]. Per stage per thread: 4x global_load_dwordx4 (f32, to regs)
// + 2x global_load_lds (B) = 6 vmcnt events, issued at distance 2.
// Head of phase s: outstanding = stages {s, s+1} = 12 -> vmcnt(6) drains stage s
// (s = NS-1: only 6 outstanding -> vmcnt(0)). A regs: 2 static sets, x2 unroll.
// ds_write of A slot s&3 at head of phase s: last readers finished phase s-4. Safe.
__global__ __launch_bounds__(512)
void gemm256f(const float* __restrict__ A,            // f32, lda = 1024
              const unsigned short* __restrict__ Bt,  // [512][1024] bf16
              const float* __restrict__ bias,
              unsigned short* __restrict__ C, int ldcE, int ccol0,
              int NBN) {
  constexpr int NS = 32;                               // K=1024 / BK=32
  __shared__ __align__(16) unsigned char smem[131072];
  const int tid = threadIdx.x;
  const int lane = tid & 63, w = tid >> 6;
  const int swz = pair_swz(blockIdx.x, gridDim.x);
  const int bm = swz / NBN, bn = swz - bm * NBN;

  const int sslot = (tid & 3) ^ ((tid >> 3) & 3);      // source k-slot (pre-swizzle)
  const int srow = tid >> 2;
  // A f32 source: row (bm*256 + srow + r*128), k elems s*32 + sslot*8
  const float* aG = A + (size_t)(bm * 256 + srow) * 1024 + sslot * 8;
  const unsigned char* bG = (const unsigned char*)Bt + (size_t)(bn * 256 + srow) * 2048 + sslot * 16;
  // A LDS dest: linear (row, slot16=tid&3)
  unsigned char* laBase = smem + (srow * 64) + (tid & 3) * 16;
  unsigned char* lbBase = smem + 65536 + w * 1024;

  uint4 ra0[4], ra1[4];                                // 2 static reg sets

  auto issueA = [&](int s, uint4* ra) {
    const float* p0 = aG + (size_t)s * 32;
    ra[0] = *(const uint4*)(p0);
    ra[1] = *(const uint4*)(p0 + 4);
    ra[2] = *(const uint4*)(p0 + 128 * 1024);
    ra[3] = *(const uint4*)(p0 + 128 * 1024 + 4);
  };
  auto issueB = [&](int s) {
    const int slot = s & 3;
    const unsigned char* sb = bG + (size_t)s * 64;
    async_copy16(sb, lbBase + slot * 16384);
    async_copy16(sb + 128 * 2048, lbBase + slot * 16384 + 8192);
  };
  auto writeA = [&](int s, const uint4* ra) {
    const int slot = s & 3;
#pragma unroll
    for (int r = 0; r < 2; r++) {
      float x0 = fmaxf(__uint_as_float(ra[2 * r].x), 0.f);
      float x1 = fmaxf(__uint_as_float(ra[2 * r].y), 0.f);
      float x2 = fmaxf(__uint_as_float(ra[2 * r].z), 0.f);
      float x3 = fmaxf(__uint_as_float(ra[2 * r].w), 0.f);
      float x4 = fmaxf(__uint_as_float(ra[2 * r + 1].x), 0.f);
      float x5 = fmaxf(__uint_as_float(ra[2 * r + 1].y), 0.f);
      float x6 = fmaxf(__uint_as_float(ra[2 * r + 1].z), 0.f);
      float x7 = fmaxf(__uint_as_float(ra[2 * r + 1].w), 0.f);
      uint4 u;
      u.x = pack2(x0, x1); u.y = pack2(x2, x3);
      u.z = pack2(x4, x5); u.w = pack2(x6, x7);
      *(uint4*)(laBase + slot * 16384 + r * 8192) = u;
    }
  };

  const int wm = w >> 2, wn = w & 3;
  const int frow = lane & 15;
  const int colb = (((lane >> 4) ^ ((frow >> 1) & 3)) << 4);
  const int aRowB = (wm * 128 + frow) * 64;
  const int bRowB = (wn * 64 + frow) * 64;

  f32x4 acc[8][4];
#pragma unroll
  for (int m = 0; m < 8; m++)
#pragma unroll
    for (int n = 0; n < 4; n++) acc[m][n] = (f32x4){0.f, 0.f, 0.f, 0.f};

  // prologue: stages 0 (set0) and 1 (set1)
  issueA(0, ra0); issueB(0);
  issueA(1, ra1); issueB(1);

#pragma unroll 1
  for (int s = 0; s < NS; s += 2) {
#pragma unroll
    for (int half = 0; half < 2; half++) {
      const int sc = s + half;
      uint4* raC = half ? ra1 : ra0;
      if (sc == NS - 1) asm volatile("s_waitcnt vmcnt(0)" ::: "memory");
      else              asm volatile("s_waitcnt vmcnt(6)" ::: "memory");
      __builtin_amdgcn_sched_barrier(0);
      writeA(sc, raC);                       // slot sc&3: readers done at sc-4
      if (sc + 2 < NS) { issueA(sc + 2, raC); issueB(sc + 2); }
      asm volatile("s_waitcnt lgkmcnt(0)" ::: "memory");
      __builtin_amdgcn_s_barrier();
      __builtin_amdgcn_sched_barrier(0);
      const unsigned char* ab = smem + (sc & 3) * 16384;
      const unsigned char* bb = smem + 65536 + (sc & 3) * 16384;
      bf16x8 af[8], bfv[4];
#pragma unroll
      for (int m = 0; m < 8; m++) af[m] = *(const bf16x8*)(ab + aRowB + m * 1024 + colb);
#pragma unroll
      for (int n = 0; n < 4; n++) bfv[n] = *(const bf16x8*)(bb + bRowB + n * 1024 + colb);
      __builtin_amdgcn_s_setprio(1);
#pragma unroll
      for (int m = 0; m < 8; m++)
#pragma unroll
        for (int n = 0; n < 4; n++)
          acc[m][n] = __builtin_amdgcn_mfma_f32_16x16x32_bf16(af[m], bfv[n], acc[m][n], 0, 0, 0);
      __builtin_amdgcn_s_setprio(0);
      __builtin_amdgcn_sched_barrier(0);
      __builtin_amdgcn_s_barrier();          // keep skew <=1 phase before next writeA
    }
  }
  const int rb = bm * 256 + wm * 128 + ((lane >> 4) << 2);
  const int cb = bn * 256 + wn * 64 + frow;
#pragma unroll
  for (int n = 0; n < 4; n++) {
    const int col = cb + n * 16;
    const float bv = bias[col];
#pragma unroll
    for (int m = 0; m < 8; m++)
#pragma unroll
      for (int i = 0; i < 4; i++) {
        const int row = rb + m * 16 + i;
        C[(size_t)row * ldcE + ccol0 + col] = f2b(acc[m][n][i] + bv);
      }
  }
}

// ---- 128x128 m97-structure GEMM for cls layer (N=50) + fused score scatter ----
__global__ __launch_bounds__(256)
void gemm_cls(const unsigned short* __restrict__ A, int lda,
              const unsigned short* __restrict__ Bt,
              const float* __restrict__ bias,
              float* __restrict__ C,
              int Ktot,
              const int* __restrict__ pidx,
              unsigned long long* __restrict__ scat) {
  __shared__ unsigned short ldsA[128 * 64];
  __shared__ unsigned short ldsB[128 * 64];
  const int tid = threadIdx.x;
  const int lane = tid & 63, wid = tid >> 6;
  const int cpx = gridDim.x >> 3;
  const int bm = (blockIdx.x & 7) * cpx + (blockIdx.x >> 3);

  const int srow = wid * 32 + (lane >> 3);
  const int skof = (lane & 7) * 8;
  const unsigned short* ag = A + (size_t)(bm * 128 + srow) * lda + skof;
  const unsigned short* bg = Bt + (size_t)srow * Ktot + skof;

  f32x4 acc[4][4];
#pragma unroll
  for (int m = 0; m < 4; m++)
#pragma unroll
    for (int n = 0; n < 4; n++) acc[m][n] = (f32x4){0.f, 0.f, 0.f, 0.f};

  const int wm = wid >> 1, wn = wid & 1;
  const int frow = lane & 15;
  const int kgrp = (lane >> 4) << 3;

  for (int kt = 0; kt < Ktot; kt += 64) {
#pragma unroll
    for (int i = 0; i < 4; i++) {
      async_copy16(ag + (size_t)i * 8 * lda + kt, &ldsA[wid * 2048 + i * 512]);
      async_copy16(bg + (size_t)i * 8 * Ktot + kt, &ldsB[wid * 2048 + i * 512]);
    }
    __syncthreads();
#pragma unroll
    for (int kk = 0; kk < 64; kk += 32) {
      bf16x8 af[4], bfr[4];
#pragma unroll
      for (int m = 0; m < 4; m++)
        af[m] = *(const bf16x8*)&ldsA[(wm * 64 + m * 16 + frow) * 64 + kk + kgrp];
#pragma unroll
      for (int n = 0; n < 4; n++)
        bfr[n] = *(const bf16x8*)&ldsB[(wn * 64 + n * 16 + frow) * 64 + kk + kgrp];
#pragma unroll
      for (int m = 0; m < 4; m++)
#pragma unroll
        for (int n = 0; n < 4; n++)
          acc[m][n] = __builtin_amdgcn_mfma_f32_16x16x32_bf16(af[m], bfr[n], acc[m][n], 0, 0, 0);
    }
    __syncthreads();
  }
  const int rb = bm * 128 + wm * 64 + ((lane >> 4) << 2);
#pragma unroll
  for (int n = 0; n < 4; n++) {
    const int col = wn * 64 + frow + n * 16;
    const float bv = (col < OUTC) ? bias[col] : 0.f;
#pragma unroll
    for (int m = 0; m < 4; m++)
#pragma unroll
      for (int i = 0; i < 4; i++) {
        const int row = rb + m * 16 + i;
        if (col < OUTC) C[(size_t)row * OUTC + col] = acc[m][n][i] + bv;
      }
  }
  if (wn == 0) {
#pragma unroll
    for (int m = 0; m < 4; m++)
#pragma unroll
      for (int i = 0; i < 4; i++) {
        float mx = -1e30f;
#pragma unroll
        for (int n = 0; n < 4; n++) {
          const int col = n * 16 + frow;
          float v = acc[m][n][i] + ((col < OUTC) ? bias[col] : 0.f);
          if (col < OUTC) mx = fmaxf(mx, v);
        }
        mx = fmaxf(mx, __shfl_xor(mx, 1));
        mx = fmaxf(mx, __shfl_xor(mx, 2));
        mx = fmaxf(mx, __shfl_xor(mx, 4));
        mx = fmaxf(mx, __shfl_xor(mx, 8));
        if (frow == 0) {
          const int row = rb + m * 16 + i;
          float sc = 1.f / (1.f + expf(-mx));
          int b = row >> 12, p = row & 4095;
          int s = pidx[2 * row], o = pidx[2 * row + 1];
          unsigned long long key = (((unsigned long long)(p + 1)) << 32) |
                                   (unsigned long long)__float_as_uint(sc);
          atomicMax(&scat[((size_t)(b * N_ + s) << 7) + o], key);
        }
      }
  }
}

__global__ void relmat_kernel(const unsigned long long* __restrict__ scat, float* __restrict__ out) {
  int i = blockIdx.x * blockDim.x + threadIdx.x;
  if (i >= B_ * N_ * N_) return;
  unsigned long long v = scat[i];
  out[i] = v ? __uint_as_float((unsigned)(v & 0xffffffffu)) : 0.f;
}

extern "C" void kernel_launch(void* const* d_in, const int* in_sizes, int n_in,
                              void* d_out, int out_size, void* d_ws, size_t ws_size,
                              hipStream_t stream) {
  const float* visual_feat = (const float*)d_in[0];
  const float* box_info    = (const float*)d_in[1];
  const float* pred_logits = (const float*)d_in[2];
  const int*   pair_idx    = (const int*)d_in[3];
  const float* obj_sem_w   = (const float*)d_in[4];
  const float* pos_w1 = (const float*)d_in[5];
  const float* pos_b1 = (const float*)d_in[6];
  const float* pos_w2 = (const float*)d_in[7];
  const float* pos_b2 = (const float*)d_in[8];
  const float* vis_w  = (const float*)d_in[9];
  const float* vis_b  = (const float*)d_in[10];
  const float* geo_w  = (const float*)d_in[11];
  const float* geo_b  = (const float*)d_in[12];
  const float* fus_g  = (const float*)d_in[13];
  const float* fus_bt = (const float*)d_in[14];
  const float* fus_w  = (const float*)d_in[15];
  const float* fus_b  = (const float*)d_in[16];
  const float* cls_g  = (const float*)d_in[17];
  const float* cls_bt = (const float*)d_in[18];
  const float* cls_w  = (const float*)d_in[19];
  const float* cls_b  = (const float*)d_in[20];

  char* ws = (char*)d_ws;
  size_t off = 0;
  auto alloc = [&](size_t bytes) { char* p = ws + off; off += (bytes + 255) & ~(size_t)255; return p; };
  unsigned short* fused = (unsigned short*)alloc((size_t)M_ * 1024 * 2);      // 134 MB
  unsigned short* fused2 = (unsigned short*)alloc((size_t)M_ * 512 * 2);      // 67 MB
  unsigned short* nodeFb = (unsigned short*)alloc((size_t)B_ * N_ * NODEF * 2);
  unsigned short* wT_vis = (unsigned short*)alloc((size_t)512 * 1024 * 2);
  unsigned short* wT_geo = (unsigned short*)alloc((size_t)512 * KGEOP * 2);
  unsigned short* wT_fus = (unsigned short*)alloc((size_t)512 * 1024 * 2);
  unsigned short* wT_cls = (unsigned short*)alloc((size_t)128 * 512 * 2);
  unsigned long long* scat = (unsigned long long*)alloc((size_t)B_ * N_ * N_ * 8);

  float* out_logits = (float*)d_out;
  float* out_rel = out_logits + (size_t)M_ * OUTC;

  prep_kernel<<<dim3((PREP_TOT + 255) / 256), 256, 0, stream>>>(
      (uint4*)scat, vis_w, wT_vis, geo_w, wT_geo, fus_w, wT_fus, cls_w, wT_cls);
  node_kernel<<<dim3(B_ * N_), 128, 0, stream>>>(box_info, pred_logits, obj_sem_w,
                                                 pos_w1, pos_b1, pos_w2, pos_b2, nodeFb);
  gemm256r<1><<<dim3(512), 512, 0, stream>>>(nullptr, 0, wT_geo, KGEOP, geo_b,
                                             fused, 1024, 512, KGEOP / 32, 2,
                                             pair_idx, nodeFb, (const unsigned short*)scat);
  gemm256f<<<dim3(512), 512, 0, stream>>>(visual_feat, wT_vis, vis_b,
                                          fused, 1024, 0, 2);
  ln_relu_kernel<1024><<<dim3(M_ / 4), 256, 0, stream>>>(fused, fus_g, fus_bt);
  gemm256r<0><<<dim3(512), 512, 0, stream>>>(fused, 1024, wT_fus, 1024, fus_b,
                                             fused2, 512, 0, 1024 / 32, 2,
                                             nullptr, nullptr, nullptr);
  ln_relu_kernel<512><<<dim3(M_ / 4), 256, 0, stream>>>(fused2, cls_g, cls_bt);
  gemm_cls<<<dim3(512), 256, 0, stream>>>(fused2, 512, wT_cls, cls_b,
                                          out_logits, 512, pair_idx, scat);
  relmat_kernel<<<dim3((B_ * N_ * N_) / 256), 256, 0, stream>>>(scat, out_rel);
}